// Round 10
// baseline (201.119 us; speedup 1.0000x reference)
//
#include <hip/hip_runtime.h>

#define TOPK 32

typedef float vfloat4 __attribute__((ext_vector_type(4)));

// ---------------------------------------------------------------------------
// K0: per-batch histogram of pos -> counts. B blocks, LDS atomics. ~4us.
// Writes every counts entry (no memset needed).
// ---------------------------------------------------------------------------
__global__ void hist_kernel(const int* __restrict__ pos,
                            int* __restrict__ counts,
                            int S) {
    extern __shared__ int cnt[];          // S ints
    int b = blockIdx.x;
    int t = threadIdx.x;
    for (int i = t; i < S; i += 256) cnt[i] = 0;
    __syncthreads();
    for (int i = t; i < S; i += 256)
        atomicAdd(&cnt[pos[(size_t)b * S + i]], 1);
    __syncthreads();
    for (int i = t; i < S; i += 256)
        counts[(size_t)b * S + i] = cnt[i];
}

// ---------------------------------------------------------------------------
// K1: one wave per row; dot ONLY for referenced rows (count>0, ~63%).
//   d2[row] = dot(base[row,:], W[b,:])
// ---------------------------------------------------------------------------
__global__ void dot_kernel(const float* __restrict__ base,
                           const float* __restrict__ bw,
                           const int* __restrict__ counts,
                           float* __restrict__ d2,
                           int S, int H) {
    int wid  = (blockIdx.x * blockDim.x + threadIdx.x) >> 6;  // row = b*S + p
    int lane = threadIdx.x & 63;
    if (counts[wid] == 0) return;
    int b = wid / S;

    const float4* row = (const float4*)(base + (size_t)wid * H);
    const float4* w4  = (const float4*)(bw + (size_t)b * H);
    int n4 = H >> 2;                      // 512

    float acc = 0.f;
    #pragma unroll 8
    for (int i = lane; i < n4; i += 64) {
        float4 v = row[i];
        float4 w = w4[i];
        acc += v.x * w.x + v.y * w.y + v.z * w.z + v.w * w.w;
    }
    #pragma unroll
    for (int off = 32; off > 0; off >>= 1)
        acc += __shfl_down(acc, off, 64);

    if (lane == 0) d2[wid] = acc;
}

// ---------------------------------------------------------------------------
// K2-mega: 1024 blocks, all co-resident (launch_bounds(256,4): VGPR<=128,
// LDS 32KB -> 4-5 blocks/CU).
//  blocks 0..B-1 : gather d2 -> detect, exact top-32 (single wave,
//                  ties->lower idx), nontopk; write meanv[b], threadfence,
//                  release-increment `done`.
//  blocks B..    : (1) sweep-copy mixed=base for count==0 rows (~94MB each
//                  way) -- this hides the topk; (2) one acquire-poll until
//                  done==B (expected already satisfied); (3) sweep-mix
//                  count>0 rows: mixed = base + count*mean*W.
// NOT a grid barrier: consumers poll only after their copy sweep, producers
// never wait. One-shot flag, s_sleep backoff -> no R8-style BW collapse.
// ---------------------------------------------------------------------------
__global__ __launch_bounds__(256, 4)
void topk_copy_mix_kernel(const float* __restrict__ d2,
                          const int* __restrict__ pos,
                          const int* __restrict__ counts,
                          const float* __restrict__ base,
                          const float* __restrict__ bw,
                          float* __restrict__ mixed,
                          float* __restrict__ detect,
                          float* __restrict__ nontopk,
                          float* __restrict__ meanv,
                          int* __restrict__ done,
                          int B, int S, int H, int ncopy) {
    __shared__ float smem[8192];          // dvals[S] + vals[S], S==4096
    const int t = threadIdx.x;
    const int n4 = H >> 2;                // 512
    const int nrows = B * S;

    if (blockIdx.x < B) {
        // ---------------- top-k producer ----------------
        float* dvals = smem;
        float* vals  = smem + S;
        int b = blockIdx.x;

        for (int i = t; i < S; i += 256)
            dvals[i] = d2[(size_t)b * S + i];
        __syncthreads();
        for (int i = t; i < S; i += 256) {
            float v = fmaxf(dvals[pos[(size_t)b * S + i]], 0.f);
            vals[i] = v;
            detect[(size_t)b * S + i] = v;
        }
        __syncthreads();

        if (t < 64) {                     // single wave: barrier-free top-k
            int lane = t;
            float sum = 0.f;
            for (int it = 0; it < TOPK; ++it) {
                float lv = -INFINITY;
                int   li = 0x7fffffff;
                for (int c = lane * 4; c < S; c += 256) {
                    float4 v = *(const float4*)&vals[c];
                    if (v.x > lv) { lv = v.x; li = c; }
                    if (v.y > lv) { lv = v.y; li = c + 1; }
                    if (v.z > lv) { lv = v.z; li = c + 2; }
                    if (v.w > lv) { lv = v.w; li = c + 3; }
                }
                #pragma unroll
                for (int off = 32; off > 0; off >>= 1) {
                    float ov = __shfl_down(lv, off, 64);
                    int   oi = __shfl_down(li, off, 64);
                    if (ov > lv || (ov == lv && oi < li)) { lv = ov; li = oi; }
                }
                lv = __shfl(lv, 0, 64);
                li = __shfl(li, 0, 64);
                sum += lv;
                if (lane == 0) vals[li] = -INFINITY;  // wave-synchronous
            }
            if (lane == 0) meanv[b] = sum / (float)TOPK;  // t==0 writes
        }
        __syncthreads();
        if (t == 0) {                     // publish mean for this batch
            __threadfence();
            __hip_atomic_fetch_add(done, 1, __ATOMIC_RELEASE,
                                   __HIP_MEMORY_SCOPE_AGENT);
        }
        for (int i = t; i < S; i += 256) {
            float v = vals[i];
            nontopk[(size_t)b * S + i] = (v == -INFINITY) ? 0.f : v;
        }
    } else {
        // ---------------- copy + mix consumer ----------------
        const int start = blockIdx.x - B;

        // (1) copy count==0 rows (needs no mean) -- hides the top-k
        for (int row = start; row < nrows; row += ncopy) {
            if (counts[row] != 0) continue;
            const vfloat4* bp = (const vfloat4*)(base + (size_t)row * H);
            vfloat4*       op = (vfloat4*)(mixed + (size_t)row * H);
            #pragma unroll 2
            for (int i = t; i < n4; i += 256) {
                vfloat4 v = __builtin_nontemporal_load(&bp[i]);
                __builtin_nontemporal_store(v, &op[i]);
            }
        }

        // (2) wait until all B means are published (expected: already done)
        if (t == 0) {
            while (__hip_atomic_load(done, __ATOMIC_ACQUIRE,
                                     __HIP_MEMORY_SCOPE_AGENT) < B)
                __builtin_amdgcn_s_sleep(16);
        }
        __syncthreads();

        // (3) mix count>0 rows
        for (int row = start; row < nrows; row += ncopy) {
            int c = counts[row];
            if (c == 0) continue;
            int b = row / S;
            float scale = (float)c * meanv[b];
            const float4* bp = (const float4*)(base + (size_t)row * H);
            const float4* wp = (const float4*)(bw + (size_t)b * H);
            vfloat4*      op = (vfloat4*)(mixed + (size_t)row * H);
            #pragma unroll 2
            for (int i = t; i < n4; i += 256) {
                float4 v = bp[i];
                float4 w = wp[i];
                vfloat4 o;
                o.x = v.x + scale * w.x;
                o.y = v.y + scale * w.y;
                o.z = v.z + scale * w.z;
                o.w = v.w + scale * w.w;
                __builtin_nontemporal_store(o, &op[i]);
            }
        }
    }
}

// ---------------------------------------------------------------------------
extern "C" void kernel_launch(void* const* d_in, const int* in_sizes, int n_in,
                              void* d_out, int out_size, void* d_ws, size_t ws_size,
                              hipStream_t stream) {
    const float* base = (const float*)d_in[0];
    const int*   pos  = (const int*)d_in[1];
    const float* bw   = (const float*)d_in[2];

    long n0 = in_sizes[0];               // B*S*H
    long n1 = in_sizes[1];               // B*S
    long n2 = in_sizes[2];               // B*H
    int H = (int)(n0 / n1);
    int B = (int)(n2 / H);
    int S = (int)(n1 / B);

    float* out_mixed   = (float*)d_out;
    float* out_detect  = out_mixed + (size_t)B * S * H;
    float* out_nontopk = out_detect + (size_t)B * S;

    // ws layout: [done:16 ints][counts: B*S ints][d2: B*S floats][meanv: B]
    int*   done   = (int*)d_ws;
    int*   counts = done + 16;
    float* d2     = (float*)(counts + (size_t)B * S);
    float* meanv  = d2 + (size_t)B * S;

    int nrows = B * S;
    int ncopy = 1016;                    // consumer blocks
    int grid2 = B + ncopy;               // 1024 total, all co-resident

    hipMemsetAsync(done, 0, 16 * sizeof(int), stream);   // one-shot flag
    hist_kernel<<<B, 256, (size_t)S * sizeof(int), stream>>>(pos, counts, S);
    dot_kernel<<<nrows / 4, 256, 0, stream>>>(base, bw, counts, d2, S, H);
    topk_copy_mix_kernel<<<grid2, 256, 0, stream>>>(
        d2, pos, counts, base, bw, out_mixed, out_detect, out_nontopk,
        meanv, done, B, S, H, ncopy);
}

// Round 11
// 177.679 us; speedup vs baseline: 1.1319x; 1.1319x over previous
//
#include <hip/hip_runtime.h>

#define TOPK 32

typedef float vfloat4 __attribute__((ext_vector_type(4)));

// ---------------------------------------------------------------------------
// K0: per-batch histogram of pos -> counts. B blocks, LDS atomics. ~4us.
// ---------------------------------------------------------------------------
__global__ void hist_kernel(const int* __restrict__ pos,
                            int* __restrict__ counts,
                            int S) {
    extern __shared__ int cnt[];          // S ints
    int b = blockIdx.x;
    int t = threadIdx.x;
    for (int i = t; i < S; i += 256) cnt[i] = 0;
    __syncthreads();
    for (int i = t; i < S; i += 256)
        atomicAdd(&cnt[pos[(size_t)b * S + i]], 1);
    __syncthreads();
    for (int i = t; i < S; i += 256)
        counts[(size_t)b * S + i] = cnt[i];
}

// ---------------------------------------------------------------------------
// K1: one wave per row; dot ONLY for referenced rows (count>0, ~63%).
//   d2[row] = dot(base[row,:], W[b,:])
// Cached loads on purpose: primes L3 with exactly the rows mix re-reads
// (R10 counters proved ~130MB of this survives to the later dispatch).
// ---------------------------------------------------------------------------
__global__ void dot_kernel(const float* __restrict__ base,
                           const float* __restrict__ bw,
                           const int* __restrict__ counts,
                           float* __restrict__ d2,
                           int S, int H) {
    int wid  = (blockIdx.x * blockDim.x + threadIdx.x) >> 6;  // row = b*S + p
    int lane = threadIdx.x & 63;
    if (counts[wid] == 0) return;
    int b = wid / S;

    const float4* row = (const float4*)(base + (size_t)wid * H);
    const float4* w4  = (const float4*)(bw + (size_t)b * H);
    int n4 = H >> 2;                      // 512

    float acc = 0.f;
    #pragma unroll 8
    for (int i = lane; i < n4; i += 64) {
        float4 v = row[i];
        float4 w = w4[i];
        acc += v.x * w.x + v.y * w.y + v.z * w.z + v.w * w.w;
    }
    #pragma unroll
    for (int off = 32; off > 0; off >>= 1)
        acc += __shfl_down(acc, off, 64);

    if (lane == 0) d2[wid] = acc;
}

// ---------------------------------------------------------------------------
// K2: one block per batch (B=8). Gather d2 -> detect (LDS), exact top-32 by
// a single wave (barrier-free, ties -> lower index = lax.top_k), nontopk,
// mean. ~12us exposed; accepted.
// ---------------------------------------------------------------------------
__global__ void topk_kernel(const float* __restrict__ d2,
                            const int* __restrict__ pos,
                            float* __restrict__ detect,
                            float* __restrict__ nontopk,
                            float* __restrict__ meanv,
                            int S) {
    extern __shared__ float smem[];
    float* dvals = smem;                  // S floats: d2 for this batch
    float* vals  = smem + S;              // S floats: detect (mutated)

    int b = blockIdx.x;
    int t = threadIdx.x;

    for (int i = t; i < S; i += 256)
        dvals[i] = d2[(size_t)b * S + i];
    __syncthreads();
    for (int i = t; i < S; i += 256) {
        float v = fmaxf(dvals[pos[(size_t)b * S + i]], 0.f);
        vals[i] = v;
        detect[(size_t)b * S + i] = v;
    }
    __syncthreads();

    if (t < 64) {                         // single wave: barrier-free top-k
        int lane = t;
        float sum = 0.f;
        for (int it = 0; it < TOPK; ++it) {
            float lv = -INFINITY;
            int   li = 0x7fffffff;
            for (int c = lane * 4; c < S; c += 256) {
                float4 v = *(const float4*)&vals[c];
                if (v.x > lv) { lv = v.x; li = c; }
                if (v.y > lv) { lv = v.y; li = c + 1; }
                if (v.z > lv) { lv = v.z; li = c + 2; }
                if (v.w > lv) { lv = v.w; li = c + 3; }
            }
            #pragma unroll
            for (int off = 32; off > 0; off >>= 1) {
                float ov = __shfl_down(lv, off, 64);
                int   oi = __shfl_down(li, off, 64);
                if (ov > lv || (ov == lv && oi < li)) { lv = ov; li = oi; }
            }
            lv = __shfl(lv, 0, 64);
            li = __shfl(li, 0, 64);
            sum += lv;
            if (lane == 0) vals[li] = -INFINITY;  // wave-synchronous
        }
        if (lane == 0) meanv[b] = sum / (float)TOPK;
    }
    __syncthreads();

    for (int i = t; i < S; i += 256) {
        float v = vals[i];
        nontopk[(size_t)b * S + i] = (v == -INFINITY) ? 0.f : v;
    }
}

// ---------------------------------------------------------------------------
// K3: unified branch-free mix over ALL rows (copy == mix with scale 0):
//   mixed[b,p,:] = base[b,p,:] + counts[b,p]*mean[b]*W[b,:]
// 4 consecutive rows per block, 8192 blocks. Normal loads (L3-resident rows
// from K1 hit), NT stores for the streamed output.
// ---------------------------------------------------------------------------
__global__ void mix_kernel(const float* __restrict__ base,
                           const float* __restrict__ bw,
                           const int* __restrict__ counts,
                           const float* __restrict__ meanv,
                           float* __restrict__ mixed,
                           int S, int H) {
    int r0 = blockIdx.x << 2;
    int b  = r0 / S;
    const float4* w4 = (const float4*)(bw + (size_t)b * H);
    float mb = meanv[b];
    int n4 = H >> 2;                      // 512
    int4 c4 = *(const int4*)&counts[r0];  // counts for the 4 rows

    #pragma unroll
    for (int k = 0; k < 4; ++k) {
        int r = r0 + k;
        int c = (k == 0) ? c4.x : (k == 1) ? c4.y : (k == 2) ? c4.z : c4.w;
        float scale = (float)c * mb;      // 0 for unreferenced rows -> copy
        const float4* b4 = (const float4*)(base + (size_t)r * H);
        vfloat4*      o4 = (vfloat4*)(mixed + (size_t)r * H);
        #pragma unroll 2
        for (int i = threadIdx.x; i < n4; i += blockDim.x) {
            float4 v = b4[i];
            float4 w = w4[i];
            vfloat4 o;
            o.x = v.x + scale * w.x;
            o.y = v.y + scale * w.y;
            o.z = v.z + scale * w.z;
            o.w = v.w + scale * w.w;
            __builtin_nontemporal_store(o, &o4[i]);
        }
    }
}

// ---------------------------------------------------------------------------
extern "C" void kernel_launch(void* const* d_in, const int* in_sizes, int n_in,
                              void* d_out, int out_size, void* d_ws, size_t ws_size,
                              hipStream_t stream) {
    const float* base = (const float*)d_in[0];
    const int*   pos  = (const int*)d_in[1];
    const float* bw   = (const float*)d_in[2];

    long n0 = in_sizes[0];               // B*S*H
    long n1 = in_sizes[1];               // B*S
    long n2 = in_sizes[2];               // B*H
    int H = (int)(n0 / n1);
    int B = (int)(n2 / H);
    int S = (int)(n1 / B);

    float* out_mixed   = (float*)d_out;
    float* out_detect  = out_mixed + (size_t)B * S * H;
    float* out_nontopk = out_detect + (size_t)B * S;

    int*   counts = (int*)d_ws;
    float* d2     = (float*)((char*)d_ws + (size_t)B * S * sizeof(int));
    float* meanv  = (float*)((char*)d_ws + 2 * (size_t)B * S * sizeof(int));

    int nrows = B * S;

    hist_kernel<<<B, 256, (size_t)S * sizeof(int), stream>>>(pos, counts, S);
    dot_kernel<<<nrows / 4, 256, 0, stream>>>(base, bw, counts, d2, S, H);
    topk_kernel<<<B, 256, 2 * (size_t)S * sizeof(float), stream>>>(
        d2, pos, out_detect, out_nontopk, meanv, S);
    mix_kernel<<<nrows / 4, 256, 0, stream>>>(base, bw, counts, meanv, out_mixed, S, H);
}

// Round 12
// 173.473 us; speedup vs baseline: 1.1594x; 1.0242x over previous
//
#include <hip/hip_runtime.h>

#define TOPK 32

typedef float vfloat4 __attribute__((ext_vector_type(4)));

// ---------------------------------------------------------------------------
// K0: per-batch histogram + compaction. One block per batch.
//  counts[b,i]  = multiplicity of i in pos[b,:]
//  refList[b,:]  = ascending i with count>0   (nrefb[b] entries)
//  zeroList[b,:] = ascending i with count==0  (S-nrefb[b] entries)
// Block-level prefix sum (256 threads x 16-elem chunks) keeps order.
// ---------------------------------------------------------------------------
__global__ void hist_compact_kernel(const int* __restrict__ pos,
                                    int* __restrict__ counts,
                                    int* __restrict__ refList,
                                    int* __restrict__ zeroList,
                                    int* __restrict__ nrefb,
                                    int S) {
    extern __shared__ int cnt[];          // S ints
    __shared__ int partial[256];
    int b = blockIdx.x, t = threadIdx.x;
    const int CH = S >> 8;                // 16

    for (int i = t; i < S; i += 256) cnt[i] = 0;
    __syncthreads();
    for (int i = t; i < S; i += 256)
        atomicAdd(&cnt[pos[(size_t)b * S + i]], 1);
    __syncthreads();

    int base_i = t * CH;
    int loc = 0;
    for (int k = 0; k < CH; ++k) loc += (cnt[base_i + k] > 0);
    partial[t] = loc;
    __syncthreads();
    for (int off = 1; off < 256; off <<= 1) {   // Hillis-Steele inclusive scan
        int add = (t >= off) ? partial[t - off] : 0;
        __syncthreads();
        partial[t] += add;
        __syncthreads();
    }
    int excl = partial[t] - loc;          // refs strictly before my chunk

    int run = 0;
    for (int k = 0; k < CH; ++k) {
        int i = base_i + k;
        int c = cnt[i];
        counts[(size_t)b * S + i] = c;
        int refpos = excl + run;          // refs strictly before i
        if (c > 0) { refList[(size_t)b * S + refpos] = i; ++run; }
        else       { zeroList[(size_t)b * S + (i - refpos)] = i; }
    }
    if (t == 255) nrefb[b] = partial[255];
}

// ---------------------------------------------------------------------------
// K1: dense dot over refList. grid (S/4, B), one wave per list entry.
//   d2[b,row] = dot(base[b,row,:], W[b,:])
// Cached loads: primes L3 with exactly the rows mix re-reads (R10: ~130MB
// survives to the mix dispatch).
// ---------------------------------------------------------------------------
__global__ void dot_kernel(const float* __restrict__ base,
                           const float* __restrict__ bw,
                           const int* __restrict__ refList,
                           const int* __restrict__ nrefb,
                           float* __restrict__ d2,
                           int S, int H) {
    int b = blockIdx.y;
    int j = blockIdx.x * 4 + (threadIdx.x >> 6);
    if (j >= nrefb[b]) return;            // dense tail: retires instantly
    int lane = threadIdx.x & 63;
    int row = b * S + refList[(size_t)b * S + j];

    const float4* rp = (const float4*)(base + (size_t)row * H);
    const float4* wp = (const float4*)(bw + (size_t)b * H);
    int n4 = H >> 2;                      // 512

    float acc = 0.f;
    #pragma unroll 8
    for (int i = lane; i < n4; i += 64) {
        float4 v = rp[i];
        float4 w = wp[i];
        acc += v.x * w.x + v.y * w.y + v.z * w.z + v.w * w.w;
    }
    #pragma unroll
    for (int off = 32; off > 0; off >>= 1)
        acc += __shfl_down(acc, off, 64);

    if (lane == 0) d2[row] = acc;
}

// ---------------------------------------------------------------------------
// K2: blocks 0..B-1: per-batch gather d2 -> detect, exact top-32 by a single
//     wave (ties -> lower index = lax.top_k), nontopk, mean.
//     blocks B.. : dense copy mixed=base over zeroList (NT both ways; hides
//     the serial top-k, keeps L3 clean for mix's refs).
// ---------------------------------------------------------------------------
__global__ void topk_copy_kernel(const float* __restrict__ d2,
                                 const int* __restrict__ pos,
                                 const int* __restrict__ zeroList,
                                 const int* __restrict__ nrefb,
                                 const float* __restrict__ base,
                                 float* __restrict__ mixed,
                                 float* __restrict__ detect,
                                 float* __restrict__ nontopk,
                                 float* __restrict__ meanv,
                                 int B, int S, int H, int ncopy) {
    __shared__ float smem[8192];          // dvals[S] + vals[S], S==4096
    int t = threadIdx.x;

    if (blockIdx.x < B) {
        float* dvals = smem;
        float* vals  = smem + S;
        int b = blockIdx.x;

        for (int i = t; i < S; i += 256)
            dvals[i] = d2[(size_t)b * S + i];
        __syncthreads();
        for (int i = t; i < S; i += 256) {
            float v = fmaxf(dvals[pos[(size_t)b * S + i]], 0.f);
            vals[i] = v;
            detect[(size_t)b * S + i] = v;
        }
        __syncthreads();

        if (t < 64) {                     // single wave: barrier-free top-k
            int lane = t;
            float sum = 0.f;
            for (int it = 0; it < TOPK; ++it) {
                float lv = -INFINITY;
                int   li = 0x7fffffff;
                for (int c = lane * 4; c < S; c += 256) {
                    float4 v = *(const float4*)&vals[c];
                    if (v.x > lv) { lv = v.x; li = c; }
                    if (v.y > lv) { lv = v.y; li = c + 1; }
                    if (v.z > lv) { lv = v.z; li = c + 2; }
                    if (v.w > lv) { lv = v.w; li = c + 3; }
                }
                #pragma unroll
                for (int off = 32; off > 0; off >>= 1) {
                    float ov = __shfl_down(lv, off, 64);
                    int   oi = __shfl_down(li, off, 64);
                    if (ov > lv || (ov == lv && oi < li)) { lv = ov; li = oi; }
                }
                lv = __shfl(lv, 0, 64);
                li = __shfl(li, 0, 64);
                sum += lv;
                if (lane == 0) vals[li] = -INFINITY;  // wave-synchronous
            }
            if (lane == 0) meanv[b] = sum / (float)TOPK;
        }
        __syncthreads();
        for (int i = t; i < S; i += 256) {
            float v = vals[i];
            nontopk[(size_t)b * S + i] = (v == -INFINITY) ? 0.f : v;
        }
    } else {
        int n4 = H >> 2;                  // 512
        int start = blockIdx.x - B;
        for (int b = 0; b < B; ++b) {
            int nz = S - nrefb[b];
            for (int j = start; j < nz; j += ncopy) {
                int row = b * S + zeroList[(size_t)b * S + j];
                const vfloat4* bp = (const vfloat4*)(base + (size_t)row * H);
                vfloat4*       op = (vfloat4*)(mixed + (size_t)row * H);
                #pragma unroll 2
                for (int i = t; i < n4; i += 256) {
                    vfloat4 v = __builtin_nontemporal_load(&bp[i]);
                    __builtin_nontemporal_store(v, &op[i]);
                }
            }
        }
    }
}

// ---------------------------------------------------------------------------
// K3: dense mix over refList. grid (S/4, B), 4 list entries per block:
//   mixed[row,:] = base[row,:] + counts[row]*mean[b]*W[b,:]
// Normal loads (L3 hits from dot), NT stores.
// ---------------------------------------------------------------------------
__global__ void mix_kernel(const float* __restrict__ base,
                           const float* __restrict__ bw,
                           const int* __restrict__ refList,
                           const int* __restrict__ nrefb,
                           const int* __restrict__ counts,
                           const float* __restrict__ meanv,
                           float* __restrict__ mixed,
                           int S, int H) {
    int b = blockIdx.y;
    int nr = nrefb[b];
    int j0 = blockIdx.x << 2;
    if (j0 >= nr) return;                 // dense tail
    float mb = meanv[b];
    const float4* wp = (const float4*)(bw + (size_t)b * H);
    int n4 = H >> 2;                      // 512

    #pragma unroll
    for (int k = 0; k < 4; ++k) {
        int j = j0 + k;
        if (j >= nr) break;
        int row = b * S + refList[(size_t)b * S + j];
        float scale = (float)counts[row] * mb;
        const float4* bp = (const float4*)(base + (size_t)row * H);
        vfloat4*      op = (vfloat4*)(mixed + (size_t)row * H);
        #pragma unroll 2
        for (int i = threadIdx.x; i < n4; i += blockDim.x) {
            float4 v = bp[i];
            float4 w = wp[i];
            vfloat4 o;
            o.x = v.x + scale * w.x;
            o.y = v.y + scale * w.y;
            o.z = v.z + scale * w.z;
            o.w = v.w + scale * w.w;
            __builtin_nontemporal_store(o, &op[i]);
        }
    }
}

// ---------------------------------------------------------------------------
extern "C" void kernel_launch(void* const* d_in, const int* in_sizes, int n_in,
                              void* d_out, int out_size, void* d_ws, size_t ws_size,
                              hipStream_t stream) {
    const float* base = (const float*)d_in[0];
    const int*   pos  = (const int*)d_in[1];
    const float* bw   = (const float*)d_in[2];

    long n0 = in_sizes[0];               // B*S*H
    long n1 = in_sizes[1];               // B*S
    long n2 = in_sizes[2];               // B*H
    int H = (int)(n0 / n1);
    int B = (int)(n2 / H);
    int S = (int)(n1 / B);

    float* out_mixed   = (float*)d_out;
    float* out_detect  = out_mixed + (size_t)B * S * H;
    float* out_nontopk = out_detect + (size_t)B * S;

    // ws layout: [nrefb: 16][counts: BS][refList: BS][zeroList: BS][d2: BS][meanv: B]
    size_t BS = (size_t)B * S;
    int*   nrefb    = (int*)d_ws;
    int*   counts   = nrefb + 16;
    int*   refList  = counts + BS;
    int*   zeroList = refList + BS;
    float* d2       = (float*)(zeroList + BS);
    float* meanv    = d2 + BS;

    int ncopy = 1016;
    dim3 grid2d(S / 4, B);

    hist_compact_kernel<<<B, 256, (size_t)S * sizeof(int), stream>>>(
        pos, counts, refList, zeroList, nrefb, S);
    dot_kernel<<<grid2d, 256, 0, stream>>>(base, bw, refList, nrefb, d2, S, H);
    topk_copy_kernel<<<B + ncopy, 256, 0, stream>>>(
        d2, pos, zeroList, nrefb, base, out_mixed, out_detect, out_nontopk,
        meanv, B, S, H, ncopy);
    mix_kernel<<<grid2d, 256, 0, stream>>>(
        base, bw, refList, nrefb, counts, meanv, out_mixed, S, H);
}